// Round 13
// baseline (163.042 us; speedup 1.0000x reference)
//
#include <hip/hip_runtime.h>

#define T_ 4
#define B_ 32
#define C_ 384
#define N_ 256
#define NH_ 8
#define DH_ 48
#define CG_ 48                          // C_/8
#define WELE_ 147456                    // C_*C_
#define FRAGS_M_ 442368                 // 24 o16 * 12 k32 * 3 planes * 512 u16
#define ELEMS_ ((size_t)T_*B_*C_*N_)    // 12582912 per tensor

typedef __bf16 bf16x8 __attribute__((ext_vector_type(8)));
typedef float  f32x4  __attribute__((ext_vector_type(4)));
typedef unsigned int u32x4 __attribute__((ext_vector_type(4)));
typedef unsigned int u32x2 __attribute__((ext_vector_type(2)));
typedef unsigned short u16;

__device__ __forceinline__ float bf2f(u16 h){
  unsigned u = ((unsigned)h) << 16;
  return __builtin_bit_cast(float, u);
}
__device__ __forceinline__ u16 f2bf(float f){
  unsigned u = __builtin_bit_cast(unsigned, f);
  u += 0x7FFFu + ((u >> 16) & 1u);
  return (u16)(u >> 16);
}

// K01 fused: blocks 0..287 = weight split (k0), blocks 288..1823 = input LIF (k1).
// k0: ws[m][o16][k32][plane][lane][8], elem = W[o16*16+(lane&15)][k32*32+(lane>>4)*8+e]
// k1: shortcut LIF on fp32 x -> bf16 spikes, packed [t][b][cg][n][8ci]
__global__ __launch_bounds__(256) void k01_prep(
    const float* __restrict__ x,
    const float* __restrict__ wq, const float* __restrict__ wk,
    const float* __restrict__ wv, const float* __restrict__ wp,
    u16* __restrict__ ws, u16* __restrict__ xs)
{
  const int blk = blockIdx.x;
  if (blk < 288){
    const int m = blk / 72;
    const int tid = (blk % 72) * 256 + threadIdx.x;     // 0..18431
    const float* W = (m == 0) ? wq : (m == 1) ? wk : (m == 2) ? wv : wp;
    const int fo   = tid / 768;
    const int rem  = tid % 768;
    const int k32  = rem / 64;
    const int lane = rem % 64;
    const int row  = fo*16 + (lane & 15);
    const int col  = k32*32 + (lane >> 4)*8;
    const float* src = W + (size_t)row*C_ + col;

    u16 hi8[8], mi8[8], lo8[8];
#pragma unroll
    for (int e = 0; e < 8; e++){
      float w = src[e];
      u16 hi = f2bf(w);  float r1 = w  - bf2f(hi);
      u16 mi = f2bf(r1); float r2 = r1 - bf2f(mi);
      u16 lo = f2bf(r2);
      hi8[e] = hi; mi8[e] = mi; lo8[e] = lo;
    }
    u16* dst = ws + (size_t)m*FRAGS_M_ + (size_t)((fo*12 + k32)*3)*512 + (size_t)lane*8;
    u32x4 pk;
#pragma unroll
    for (int p = 0; p < 3; p++){
      const u16* s = (p == 0) ? hi8 : (p == 1) ? mi8 : lo8;
      pk[0] = (unsigned)s[0] | ((unsigned)s[1] << 16);
      pk[1] = (unsigned)s[2] | ((unsigned)s[3] << 16);
      pk[2] = (unsigned)s[4] | ((unsigned)s[5] << 16);
      pk[3] = (unsigned)s[6] | ((unsigned)s[7] << 16);
      *(u32x4*)(dst + (size_t)p*512) = pk;
    }
  } else {
    const int bid = blk - 288;          // 0..1535
    const int b = bid / CG_, cg = bid % CG_;
    const int n = threadIdx.x;
    const int c0 = cg * 8;
    float v[8];
#pragma unroll
    for (int i = 0; i < 8; i++) v[i] = 0.f;
#pragma unroll
    for (int t = 0; t < T_; t++){
      const float* xp = x + (((size_t)(t*B_ + b))*C_ + c0)*N_ + n;
      u16 sp[8];
#pragma unroll
      for (int i = 0; i < 8; i++){
        float xv = xp[(size_t)i * N_];
        float vv = v[i] + (xv - v[i]) * 0.5f;
        bool s = vv >= 1.0f;
        sp[i] = s ? (u16)0x3F80u : (u16)0u;
        v[i] = s ? 0.f : vv;
      }
      u32x4 pk;
      pk[0] = (unsigned)sp[0] | ((unsigned)sp[1] << 16);
      pk[1] = (unsigned)sp[2] | ((unsigned)sp[3] << 16);
      pk[2] = (unsigned)sp[4] | ((unsigned)sp[5] << 16);
      pk[3] = (unsigned)sp[6] | ((unsigned)sp[7] << 16);
      *(u32x4*)(xs + ((size_t)((t*B_ + b)*CG_ + cg))*2048 + (size_t)n*8) = pk;
    }
  }
}

// K2: fused q/k/v conv1x1 (16x16x32, 3-plane split) + BN + LIF.  [R7 structure: best measured]
// q/k branches write packed spikes; v branch writes fp32 head-layout vout DIRECTLY
// (each f32x4 store instruction covers 16 full 64B lines -> no write RMW; k5 eliminated).
// t INSIDE k-loop, wave tile 32o x 32n, XCD-swizzled flat grid 2304, 4 waves.
__global__ __launch_bounds__(256) void k2_branch(
    const u16* __restrict__ xs, const u16* __restrict__ wsplit,
    const float* __restrict__ gq, const float* __restrict__ beq, const float* __restrict__ mq, const float* __restrict__ vaq,
    const float* __restrict__ gk, const float* __restrict__ bek, const float* __restrict__ mk, const float* __restrict__ vak,
    const float* __restrict__ gv, const float* __restrict__ bev, const float* __restrict__ mv, const float* __restrict__ vav,
    u16* __restrict__ qspk, u16* __restrict__ kspk, float* __restrict__ vout)
{
  const int id   = blockIdx.x;          // 0..2303
  const int xcd  = id & 7;
  const int rest = id >> 3;             // 0..287
  const int obi  = rest % 18;           // o-tile of 64
  const int nb4  = (rest / 18) & 3;     // n-tile of 64
  const int bloc = rest / 72;           // 0..3
  const int b    = xcd * 4 + bloc;
  const int ob   = obi * 64;
  const int nb   = nb4 * 64;

  const int lane = threadIdx.x & 63;
  const int w = threadIdx.x >> 6;
  const int wo = w & 1, wn = w >> 1;
  const int l15 = lane & 15, lg = lane >> 4;
  const int branch = ob / C_;
  const int obr = (ob % C_) + wo * 32;       // branch-local o base for this wave
  const int fo  = obr >> 4;                  // fragment o16 index; this wave: fo, fo+1

  const float *G, *Be, *M, *Va; u16* spdst;
  if (branch == 0){ G=gq; Be=beq; M=mq; Va=vaq; spdst=qspk; }
  else if (branch == 1){ G=gk; Be=bek; M=mk; Va=vak; spdst=kspk; }
  else { G=gv; Be=bev; M=mv; Va=vav; spdst=nullptr; }

  const u16* Wb = wsplit + (size_t)branch*FRAGS_M_ + (size_t)lane*8;
  const int nbl = nb + wn * 32;              // this wave's 32-wide n base

  // per-t spike base (lane-resolved): + k*8192 + in*128 gives the B-fragment
  const u16* xbt[T_];
#pragma unroll
  for (int t = 0; t < T_; t++)
    xbt[t] = xs + ((size_t)((t*B_ + b)*CG_) + lg)*2048 + (size_t)(nbl + l15)*8;

  f32x4 acc[T_][2][2];
#pragma unroll
  for (int t = 0; t < T_; t++)
#pragma unroll
    for (int io = 0; io < 2; io++)
#pragma unroll
      for (int in = 0; in < 2; in++) acc[t][io][in] = (f32x4){0.f,0.f,0.f,0.f};

  for (int k = 0; k < 12; k++){
    bf16x8 wf[2][3];           // [io][plane: 0 hi,1 mid,2 lo]
#pragma unroll
    for (int io = 0; io < 2; io++)
#pragma unroll
      for (int p = 0; p < 3; p++)
        wf[io][p] = *(const bf16x8*)(Wb + (size_t)(((fo + io)*12 + k)*3 + p)*512);

#pragma unroll
    for (int t = 0; t < T_; t++){
      bf16x8 bb[2];
#pragma unroll
      for (int in = 0; in < 2; in++)
        bb[in] = *(const bf16x8*)(xbt[t] + (size_t)k*8192 + in*128);
#pragma unroll
      for (int in = 0; in < 2; in++){
        acc[t][0][in] = __builtin_amdgcn_mfma_f32_16x16x32_bf16(wf[0][2], bb[in], acc[t][0][in], 0, 0, 0);
        acc[t][0][in] = __builtin_amdgcn_mfma_f32_16x16x32_bf16(wf[0][1], bb[in], acc[t][0][in], 0, 0, 0);
        acc[t][0][in] = __builtin_amdgcn_mfma_f32_16x16x32_bf16(wf[0][0], bb[in], acc[t][0][in], 0, 0, 0);
        acc[t][1][in] = __builtin_amdgcn_mfma_f32_16x16x32_bf16(wf[1][2], bb[in], acc[t][1][in], 0, 0, 0);
        acc[t][1][in] = __builtin_amdgcn_mfma_f32_16x16x32_bf16(wf[1][1], bb[in], acc[t][1][in], 0, 0, 0);
        acc[t][1][in] = __builtin_amdgcn_mfma_f32_16x16x32_bf16(wf[1][0], bb[in], acc[t][1][in], 0, 0, 0);
      }
    }
  }

  // epilogue: BN + LIF recurrence over t; packed store (q/k) or fp32 head-layout store (v)
  float sc[2][4], sh[2][4];
#pragma unroll
  for (int io = 0; io < 2; io++)
#pragma unroll
    for (int j = 0; j < 4; j++){
      int o = obr + io*16 + lg*4 + j;
      float s = G[o] / sqrtf(Va[o] + 1e-5f);
      sc[io][j] = s;
      sh[io][j] = Be[o] - __fmul_rn(M[o], s);
    }

  float vm[2][2][4];
#pragma unroll
  for (int io = 0; io < 2; io++)
#pragma unroll
    for (int in = 0; in < 2; in++)
#pragma unroll
      for (int j = 0; j < 4; j++) vm[io][in][j] = 0.f;

#pragma unroll
  for (int t = 0; t < T_; t++){
#pragma unroll
    for (int io = 0; io < 2; io++)
#pragma unroll
      for (int in = 0; in < 2; in++){
        int n = nbl + in*16 + l15;
        u16 sp[4];
        f32x4 sp4;
#pragma unroll
        for (int j = 0; j < 4; j++){
          float z = __fadd_rn(__fmul_rn(acc[t][io][in][j], sc[io][j]), sh[io][j]);
          float vv = vm[io][in][j];
          vv = vv + (z - vv) * 0.5f;
          bool s = vv >= 1.0f;
          sp[j] = s ? (u16)0x3F80u : (u16)0u;
          sp4[j] = s ? 1.0f : 0.f;
          vm[io][in][j] = s ? 0.f : vv;
        }
        int od = obr + io*16 + lg*4;
        if (branch < 2){
          u32x2 pk;
          pk[0] = (unsigned)sp[0] | ((unsigned)sp[1] << 16);
          pk[1] = (unsigned)sp[2] | ((unsigned)sp[3] << 16);
          u16* dst = spdst + (size_t)((t*B_ + b)*CG_ + (od >> 3))*2048 + (size_t)n*8 + (od & 7);
          *(u32x2*)dst = pk;
        } else {
          int h = od / DH_, d = od % DH_;
          float* dst = vout + ((size_t)(t*B_ + b)*NH_ + h)*(N_*DH_) + (size_t)n*DH_ + d;
          *(f32x4*)dst = sp4;
        }
      }
  }
}

// K3: kv = sum_n k*v per (t,b,c), LIF(0.5) over t, emit 0xFFFF/0 masks [t][b][c].
// one wave per (b, cg); k packed u16, v read from fp32 head-layout vout (output 1).
__global__ __launch_bounds__(256) void k3_kv(
    const u16* __restrict__ kspk, const float* __restrict__ vout, u16* __restrict__ kvm)
{
  const int wid  = (int)((blockIdx.x * blockDim.x + threadIdx.x) >> 6); // 0..1535
  const int lane = threadIdx.x & 63;
  const int b = wid / CG_, cg = wid % CG_;
  const int h = cg / 6, d0 = (cg % 6) * 8;
  float u[8];
#pragma unroll
  for (int i = 0; i < 8; i++) u[i] = 0.f;

#pragma unroll
  for (int t = 0; t < T_; t++){
    int cnt[8];
#pragma unroll
    for (int i = 0; i < 8; i++) cnt[i] = 0;
    const u16* kp = kspk + (size_t)((t*B_ + b)*CG_ + cg)*2048;
    const float* vp = vout + ((size_t)(t*B_ + b)*NH_ + h)*(N_*DH_) + d0;
#pragma unroll
    for (int j = 0; j < 4; j++){
      int n = j*64 + lane;
      u32x4 kk = *(const u32x4*)(kp + (size_t)n*8);
      f32x4 v0 = *(const f32x4*)(vp + (size_t)n*DH_);
      f32x4 v1 = *(const f32x4*)(vp + (size_t)n*DH_ + 4);
      cnt[0] += ((kk[0] & 0xFFFFu) && (v0[0] != 0.f)) ? 1 : 0;
      cnt[1] += ((kk[0] >> 16)     && (v0[1] != 0.f)) ? 1 : 0;
      cnt[2] += ((kk[1] & 0xFFFFu) && (v0[2] != 0.f)) ? 1 : 0;
      cnt[3] += ((kk[1] >> 16)     && (v0[3] != 0.f)) ? 1 : 0;
      cnt[4] += ((kk[2] & 0xFFFFu) && (v1[0] != 0.f)) ? 1 : 0;
      cnt[5] += ((kk[2] >> 16)     && (v1[1] != 0.f)) ? 1 : 0;
      cnt[6] += ((kk[3] & 0xFFFFu) && (v1[2] != 0.f)) ? 1 : 0;
      cnt[7] += ((kk[3] >> 16)     && (v1[3] != 0.f)) ? 1 : 0;
    }
#pragma unroll
    for (int i = 0; i < 8; i++){
#pragma unroll
      for (int off = 32; off >= 1; off >>= 1) cnt[i] += __shfl_xor(cnt[i], off, 64);
    }
    u16 mk[8];
#pragma unroll
    for (int i = 0; i < 8; i++){
      float kvf = (float)cnt[i];
      float uu = u[i] + (kvf - u[i]) * 0.5f;
      bool s = uu >= 0.5f;
      mk[i] = s ? (u16)0xFFFFu : (u16)0u;
      u[i] = s ? 0.f : uu;
    }
    if (lane == 0){
      u32x4 pk;
      pk[0] = (unsigned)mk[0] | ((unsigned)mk[1] << 16);
      pk[1] = (unsigned)mk[2] | ((unsigned)mk[3] << 16);
      pk[2] = (unsigned)mk[4] | ((unsigned)mk[5] << 16);
      pk[3] = (unsigned)mk[6] | ((unsigned)mk[7] << 16);
      *(u32x4*)(kvm + (size_t)(t*B_ + b)*C_ + cg*8) = pk;
    }
  }
}

// K4: proj conv1x1 on y = q & kvmask (hi-plane), + bias + BN + identity -> fp32 out.
// XCD-swizzled flat grid 1536: each XCD gets 16 tb values (3.1 MB q spikes L2-resident).
__global__ __launch_bounds__(256) void k4_proj(
    const u16* __restrict__ qspk, const u16* __restrict__ kvm, const u16* __restrict__ wsplit,
    const float* __restrict__ pb,
    const float* __restrict__ gp, const float* __restrict__ bep,
    const float* __restrict__ mp, const float* __restrict__ vap,
    const float* __restrict__ x, float* __restrict__ out)
{
  const int id   = blockIdx.x;          // 0..1535
  const int xcd  = id & 7;
  const int rest = id >> 3;             // 0..191
  const int obi  = rest % 6;
  const int nb2  = (rest / 6) & 1;
  const int tbl  = rest / 12;           // 0..15
  const int tb   = xcd * 16 + tbl;
  const int ob   = obi * 64;
  const int nb   = nb2 * 128;

  __shared__ __align__(16) u16 kvmask[C_];
  for (int i = threadIdx.x; i < C_; i += 256) kvmask[i] = kvm[(size_t)tb*C_ + i];
  __syncthreads();

  const int lane = threadIdx.x & 63;
  const int w = threadIdx.x >> 6;
  const int wo = w & 1, wn = w >> 1;
  const int l15 = lane & 15, lg = lane >> 4;
  const int obw = ob + wo * 32;
  const int fo  = obw >> 4;
  const int nbl = nb + wn * 64;

  const u16* Wp = wsplit + (size_t)3*FRAGS_M_ + (size_t)lane*8;   // proj, hi plane (p=0)

  float sc[2][4], sh[2][4], pbv[2][4];
#pragma unroll
  for (int io = 0; io < 2; io++)
#pragma unroll
    for (int j = 0; j < 4; j++){
      int o = obw + io*16 + lg*4 + j;
      float s = gp[o] / sqrtf(vap[o] + 1e-5f);
      sc[io][j] = s;
      sh[io][j] = bep[o] - __fmul_rn(mp[o], s);
      pbv[io][j] = pb[o];
    }

  f32x4 acc[2][4];
#pragma unroll
  for (int io = 0; io < 2; io++)
#pragma unroll
    for (int in = 0; in < 4; in++) acc[io][in] = (f32x4){0.f,0.f,0.f,0.f};

  const u16* qb = qspk + ((size_t)(tb*CG_) + lg)*2048 + (size_t)(nbl + l15)*8;

  for (int k = 0; k < 12; k++){
    bf16x8 a0 = *(const bf16x8*)(Wp + (size_t)(((fo    )*12 + k)*3)*512);
    bf16x8 a1 = *(const bf16x8*)(Wp + (size_t)(((fo + 1)*12 + k)*3)*512);
    u32x4 mv = *(const u32x4*)&kvmask[k*32 + lg*8];
    bf16x8 bb[4];
#pragma unroll
    for (int in = 0; in < 4; in++){
      u32x4 qv = *(const u32x4*)(qb + (size_t)k*8192 + in*128);
      u32x4 yv = qv & mv;
      bb[in] = __builtin_bit_cast(bf16x8, yv);
    }
#pragma unroll
    for (int in = 0; in < 4; in++){
      acc[0][in] = __builtin_amdgcn_mfma_f32_16x16x32_bf16(a0, bb[in], acc[0][in], 0, 0, 0);
      acc[1][in] = __builtin_amdgcn_mfma_f32_16x16x32_bf16(a1, bb[in], acc[1][in], 0, 0, 0);
    }
  }

#pragma unroll
  for (int io = 0; io < 2; io++)
#pragma unroll
    for (int in = 0; in < 4; in++){
      int n = nbl + in*16 + l15;
#pragma unroll
      for (int j = 0; j < 4; j++){
        int o = obw + io*16 + lg*4 + j;
        size_t off = ((size_t)tb*C_ + o)*N_ + n;
        float z = __fadd_rn(acc[io][in][j], pbv[io][j]);
        z = __fmul_rn(z, sc[io][j]);
        z = __fadd_rn(z, sh[io][j]);
        z = __fadd_rn(z, x[off]);
        out[off] = z;
      }
    }
}

extern "C" void kernel_launch(void* const* d_in, const int* in_sizes, int n_in,
                              void* d_out, int out_size, void* d_ws, size_t ws_size,
                              hipStream_t stream)
{
  (void)in_sizes; (void)n_in; (void)out_size; (void)ws_size;
  const float* x   = (const float*)d_in[0];
  const float* qw  = (const float*)d_in[1];
  const float* qg  = (const float*)d_in[2];
  const float* qbe = (const float*)d_in[3];
  const float* qm  = (const float*)d_in[4];
  const float* qva = (const float*)d_in[5];
  const float* kw  = (const float*)d_in[6];
  const float* kg  = (const float*)d_in[7];
  const float* kbe = (const float*)d_in[8];
  const float* km  = (const float*)d_in[9];
  const float* kva = (const float*)d_in[10];
  const float* vw  = (const float*)d_in[11];
  const float* vg  = (const float*)d_in[12];
  const float* vbe = (const float*)d_in[13];
  const float* vm  = (const float*)d_in[14];
  const float* vva = (const float*)d_in[15];
  const float* pw  = (const float*)d_in[16];
  const float* pb  = (const float*)d_in[17];
  const float* pg  = (const float*)d_in[18];
  const float* pbe = (const float*)d_in[19];
  const float* pm  = (const float*)d_in[20];
  const float* pva = (const float*)d_in[21];

  float* out  = (float*)d_out;
  float* vout = out + ELEMS_;          // second output: v spikes, fp32, head layout

  u16* wsplit = (u16*)d_ws;                    // 4 * FRAGS_M_ u16 = 3.54 MB
  u16* xs   = wsplit + (size_t)4*FRAGS_M_;
  u16* qspk = xs   + ELEMS_;
  u16* kspk = qspk + ELEMS_;
  u16* kvm  = kspk + ELEMS_;                   // 4*32*384 u16

  k01_prep<<<dim3(1824), 256, 0, stream>>>(x, qw, kw, vw, pw, wsplit, xs);
  k2_branch<<<dim3(2304), 256, 0, stream>>>(xs, wsplit,
      qg, qbe, qm, qva,
      kg, kbe, km, kva,
      vg, vbe, vm, vva,
      qspk, kspk, vout);
  k3_kv<<<dim3(384), 256, 0, stream>>>(kspk, vout, kvm);
  k4_proj<<<dim3(1536), 256, 0, stream>>>(qspk, kvm, wsplit,
      pb, pg, pbe, pm, pva, x, out);
}

// Round 14
// 138.635 us; speedup vs baseline: 1.1760x; 1.1760x over previous
//
#include <hip/hip_runtime.h>

#define T_ 4
#define B_ 32
#define C_ 384
#define N_ 256
#define NH_ 8
#define DH_ 48
#define CG_ 48                          // C_/8
#define WELE_ 147456                    // C_*C_
#define FRAGS_M_ 442368                 // 24 o16 * 12 k32 * 3 planes * 512 u16
#define ELEMS_ ((size_t)T_*B_*C_*N_)    // 12582912 per tensor

typedef __bf16 bf16x8 __attribute__((ext_vector_type(8)));
typedef float  f32x4  __attribute__((ext_vector_type(4)));
typedef unsigned int u32x4 __attribute__((ext_vector_type(4)));
typedef unsigned int u32x2 __attribute__((ext_vector_type(2)));
typedef unsigned short u16;

__device__ __forceinline__ float bf2f(u16 h){
  unsigned u = ((unsigned)h) << 16;
  return __builtin_bit_cast(float, u);
}
__device__ __forceinline__ u16 f2bf(float f){
  unsigned u = __builtin_bit_cast(unsigned, f);
  u += 0x7FFFu + ((u >> 16) & 1u);
  return (u16)(u >> 16);
}

// K01 fused: blocks 0..287 = weight split (k0), blocks 288..1823 = input LIF (k1).
__global__ __launch_bounds__(256) void k01_prep(
    const float* __restrict__ x,
    const float* __restrict__ wq, const float* __restrict__ wk,
    const float* __restrict__ wv, const float* __restrict__ wp,
    u16* __restrict__ ws, u16* __restrict__ xs)
{
  const int blk = blockIdx.x;
  if (blk < 288){
    const int m = blk / 72;
    const int tid = (blk % 72) * 256 + threadIdx.x;     // 0..18431
    const float* W = (m == 0) ? wq : (m == 1) ? wk : (m == 2) ? wv : wp;
    const int fo   = tid / 768;
    const int rem  = tid % 768;
    const int k32  = rem / 64;
    const int lane = rem % 64;
    const int row  = fo*16 + (lane & 15);
    const int col  = k32*32 + (lane >> 4)*8;
    const float* src = W + (size_t)row*C_ + col;

    u16 hi8[8], mi8[8], lo8[8];
#pragma unroll
    for (int e = 0; e < 8; e++){
      float w = src[e];
      u16 hi = f2bf(w);  float r1 = w  - bf2f(hi);
      u16 mi = f2bf(r1); float r2 = r1 - bf2f(mi);
      u16 lo = f2bf(r2);
      hi8[e] = hi; mi8[e] = mi; lo8[e] = lo;
    }
    u16* dst = ws + (size_t)m*FRAGS_M_ + (size_t)((fo*12 + k32)*3)*512 + (size_t)lane*8;
    u32x4 pk;
#pragma unroll
    for (int p = 0; p < 3; p++){
      const u16* s = (p == 0) ? hi8 : (p == 1) ? mi8 : lo8;
      pk[0] = (unsigned)s[0] | ((unsigned)s[1] << 16);
      pk[1] = (unsigned)s[2] | ((unsigned)s[3] << 16);
      pk[2] = (unsigned)s[4] | ((unsigned)s[5] << 16);
      pk[3] = (unsigned)s[6] | ((unsigned)s[7] << 16);
      *(u32x4*)(dst + (size_t)p*512) = pk;
    }
  } else {
    const int bid = blk - 288;          // 0..1535
    const int b = bid / CG_, cg = bid % CG_;
    const int n = threadIdx.x;
    const int c0 = cg * 8;
    float v[8];
#pragma unroll
    for (int i = 0; i < 8; i++) v[i] = 0.f;
#pragma unroll
    for (int t = 0; t < T_; t++){
      const float* xp = x + (((size_t)(t*B_ + b))*C_ + c0)*N_ + n;
      u16 sp[8];
#pragma unroll
      for (int i = 0; i < 8; i++){
        float xv = xp[(size_t)i * N_];
        float vv = v[i] + (xv - v[i]) * 0.5f;
        bool s = vv >= 1.0f;
        sp[i] = s ? (u16)0x3F80u : (u16)0u;
        v[i] = s ? 0.f : vv;
      }
      u32x4 pk;
      pk[0] = (unsigned)sp[0] | ((unsigned)sp[1] << 16);
      pk[1] = (unsigned)sp[2] | ((unsigned)sp[3] << 16);
      pk[2] = (unsigned)sp[4] | ((unsigned)sp[5] << 16);
      pk[3] = (unsigned)sp[6] | ((unsigned)sp[7] << 16);
      *(u32x4*)(xs + ((size_t)((t*B_ + b)*CG_ + cg))*2048 + (size_t)n*8) = pk;
    }
  }
}

// K2: fused q/k/v conv1x1 (16x16x32, 3-plane split) + BN + LIF.  [R7-exact: best measured 92 us]
// All branches write PACKED spikes (contiguous u32x2) — head-layout expansion is k5's job.
// t INSIDE k-loop, wave tile 32o x 32n, XCD-swizzled flat grid 2304, 4 waves.
__global__ __launch_bounds__(256) void k2_branch(
    const u16* __restrict__ xs, const u16* __restrict__ wsplit,
    const float* __restrict__ gq, const float* __restrict__ beq, const float* __restrict__ mq, const float* __restrict__ vaq,
    const float* __restrict__ gk, const float* __restrict__ bek, const float* __restrict__ mk, const float* __restrict__ vak,
    const float* __restrict__ gv, const float* __restrict__ bev, const float* __restrict__ mv, const float* __restrict__ vav,
    u16* __restrict__ qspk, u16* __restrict__ kspk, u16* __restrict__ vspk)
{
  const int id   = blockIdx.x;          // 0..2303
  const int xcd  = id & 7;
  const int rest = id >> 3;             // 0..287
  const int obi  = rest % 18;           // o-tile of 64
  const int nb4  = (rest / 18) & 3;     // n-tile of 64
  const int bloc = rest / 72;           // 0..3
  const int b    = xcd * 4 + bloc;
  const int ob   = obi * 64;
  const int nb   = nb4 * 64;

  const int lane = threadIdx.x & 63;
  const int w = threadIdx.x >> 6;
  const int wo = w & 1, wn = w >> 1;
  const int l15 = lane & 15, lg = lane >> 4;
  const int branch = ob / C_;
  const int obr = (ob % C_) + wo * 32;       // branch-local o base for this wave
  const int fo  = obr >> 4;                  // fragment o16 index; this wave: fo, fo+1

  const float *G, *Be, *M, *Va; u16* spdst;
  if (branch == 0){ G=gq; Be=beq; M=mq; Va=vaq; spdst=qspk; }
  else if (branch == 1){ G=gk; Be=bek; M=mk; Va=vak; spdst=kspk; }
  else { G=gv; Be=bev; M=mv; Va=vav; spdst=vspk; }

  const u16* Wb = wsplit + (size_t)branch*FRAGS_M_ + (size_t)lane*8;
  const int nbl = nb + wn * 32;              // this wave's 32-wide n base

  // per-t spike base (lane-resolved): + k*8192 + in*128 gives the B-fragment
  const u16* xbt[T_];
#pragma unroll
  for (int t = 0; t < T_; t++)
    xbt[t] = xs + ((size_t)((t*B_ + b)*CG_) + lg)*2048 + (size_t)(nbl + l15)*8;

  f32x4 acc[T_][2][2];
#pragma unroll
  for (int t = 0; t < T_; t++)
#pragma unroll
    for (int io = 0; io < 2; io++)
#pragma unroll
      for (int in = 0; in < 2; in++) acc[t][io][in] = (f32x4){0.f,0.f,0.f,0.f};

  for (int k = 0; k < 12; k++){
    bf16x8 wf[2][3];           // [io][plane: 0 hi,1 mid,2 lo]
#pragma unroll
    for (int io = 0; io < 2; io++)
#pragma unroll
      for (int p = 0; p < 3; p++)
        wf[io][p] = *(const bf16x8*)(Wb + (size_t)(((fo + io)*12 + k)*3 + p)*512);

#pragma unroll
    for (int t = 0; t < T_; t++){
      bf16x8 bb[2];
#pragma unroll
      for (int in = 0; in < 2; in++)
        bb[in] = *(const bf16x8*)(xbt[t] + (size_t)k*8192 + in*128);
#pragma unroll
      for (int in = 0; in < 2; in++){
        acc[t][0][in] = __builtin_amdgcn_mfma_f32_16x16x32_bf16(wf[0][2], bb[in], acc[t][0][in], 0, 0, 0);
        acc[t][0][in] = __builtin_amdgcn_mfma_f32_16x16x32_bf16(wf[0][1], bb[in], acc[t][0][in], 0, 0, 0);
        acc[t][0][in] = __builtin_amdgcn_mfma_f32_16x16x32_bf16(wf[0][0], bb[in], acc[t][0][in], 0, 0, 0);
        acc[t][1][in] = __builtin_amdgcn_mfma_f32_16x16x32_bf16(wf[1][2], bb[in], acc[t][1][in], 0, 0, 0);
        acc[t][1][in] = __builtin_amdgcn_mfma_f32_16x16x32_bf16(wf[1][1], bb[in], acc[t][1][in], 0, 0, 0);
        acc[t][1][in] = __builtin_amdgcn_mfma_f32_16x16x32_bf16(wf[1][0], bb[in], acc[t][1][in], 0, 0, 0);
      }
    }
  }

  // epilogue: BN + LIF recurrence over t, packed bf16 spike store (all branches)
  float sc[2][4], sh[2][4];
#pragma unroll
  for (int io = 0; io < 2; io++)
#pragma unroll
    for (int j = 0; j < 4; j++){
      int o = obr + io*16 + lg*4 + j;
      float s = G[o] / sqrtf(Va[o] + 1e-5f);
      sc[io][j] = s;
      sh[io][j] = Be[o] - __fmul_rn(M[o], s);
    }

  float vm[2][2][4];
#pragma unroll
  for (int io = 0; io < 2; io++)
#pragma unroll
    for (int in = 0; in < 2; in++)
#pragma unroll
      for (int j = 0; j < 4; j++) vm[io][in][j] = 0.f;

#pragma unroll
  for (int t = 0; t < T_; t++){
#pragma unroll
    for (int io = 0; io < 2; io++)
#pragma unroll
      for (int in = 0; in < 2; in++){
        int n = nbl + in*16 + l15;
        u16 sp[4];
#pragma unroll
        for (int j = 0; j < 4; j++){
          float z = __fadd_rn(__fmul_rn(acc[t][io][in][j], sc[io][j]), sh[io][j]);
          float vv = vm[io][in][j];
          vv = vv + (z - vv) * 0.5f;
          bool s = vv >= 1.0f;
          sp[j] = s ? (u16)0x3F80u : (u16)0u;
          vm[io][in][j] = s ? 0.f : vv;
        }
        u32x2 pk;
        pk[0] = (unsigned)sp[0] | ((unsigned)sp[1] << 16);
        pk[1] = (unsigned)sp[2] | ((unsigned)sp[3] << 16);
        int od = obr + io*16 + lg*4;
        u16* dst = spdst + (size_t)((t*B_ + b)*CG_ + (od >> 3))*2048 + (size_t)n*8 + (od & 7);
        *(u32x2*)dst = pk;
      }
  }
}

// K3: kv = sum_n k*v per (t,b,c) via AND, LIF(0.5) over t, emit 0xFFFF/0 masks [t][b][c].
// one wave per (b, cg); k and v packed [t][b][cg][n][8] -> symmetric coalesced reads.
__global__ __launch_bounds__(256) void k3_kv(
    const u16* __restrict__ kspk, const u16* __restrict__ vspk, u16* __restrict__ kvm)
{
  const int wid  = (int)((blockIdx.x * blockDim.x + threadIdx.x) >> 6); // 0..1535
  const int lane = threadIdx.x & 63;
  const int b = wid / CG_, cg = wid % CG_;
  float u[8];
#pragma unroll
  for (int i = 0; i < 8; i++) u[i] = 0.f;

#pragma unroll
  for (int t = 0; t < T_; t++){
    int cnt[8];
#pragma unroll
    for (int i = 0; i < 8; i++) cnt[i] = 0;
    const size_t rowoff = (size_t)((t*B_ + b)*CG_ + cg)*2048;
    const u16* kp = kspk + rowoff;
    const u16* vp = vspk + rowoff;
#pragma unroll
    for (int j = 0; j < 4; j++){
      int n = j*64 + lane;
      u32x4 kk = *(const u32x4*)(kp + (size_t)n*8);
      u32x4 vv = *(const u32x4*)(vp + (size_t)n*8);
#pragma unroll
      for (int wd = 0; wd < 4; wd++){
        unsigned both = kk[wd] & vv[wd];
        cnt[2*wd]   += (both & 0xFFFFu) ? 1 : 0;
        cnt[2*wd+1] += (both >> 16)     ? 1 : 0;
      }
    }
#pragma unroll
    for (int i = 0; i < 8; i++){
#pragma unroll
      for (int off = 32; off >= 1; off >>= 1) cnt[i] += __shfl_xor(cnt[i], off, 64);
    }
    u16 mk[8];
#pragma unroll
    for (int i = 0; i < 8; i++){
      float kvf = (float)cnt[i];
      float uu = u[i] + (kvf - u[i]) * 0.5f;
      bool s = uu >= 0.5f;
      mk[i] = s ? (u16)0xFFFFu : (u16)0u;
      u[i] = s ? 0.f : uu;
    }
    if (lane == 0){
      u32x4 pk;
      pk[0] = (unsigned)mk[0] | ((unsigned)mk[1] << 16);
      pk[1] = (unsigned)mk[2] | ((unsigned)mk[3] << 16);
      pk[2] = (unsigned)mk[4] | ((unsigned)mk[5] << 16);
      pk[3] = (unsigned)mk[6] | ((unsigned)mk[7] << 16);
      *(u32x4*)(kvm + (size_t)(t*B_ + b)*C_ + cg*8) = pk;
    }
  }
}

// K5: expand packed v spikes -> fp32 head layout [t][b][h][n][dh], contiguous 16B stores.
__global__ __launch_bounds__(256) void k5_vtrans(const u16* __restrict__ vspk, float* __restrict__ vout)
{
  const int tb = blockIdx.x, h = blockIdx.y;
  const u16* src = vspk + ((size_t)tb*CG_ + h*6)*2048;
  float* dst = vout + ((size_t)tb*NH_ + h)*(N_*DH_);
#pragma unroll
  for (int i = 0; i < 12; i++){
    int f = i*1024 + threadIdx.x*4;
    int n = f / DH_;
    int d = f - n*DH_;
    u32x2 rv = *(const u32x2*)(src + (size_t)(d >> 3)*2048 + (size_t)n*8 + (d & 7));
    f32x4 o;
    o[0] = (rv[0] & 0xFFFFu) ? 1.f : 0.f;
    o[1] = (rv[0] >> 16)     ? 1.f : 0.f;
    o[2] = (rv[1] & 0xFFFFu) ? 1.f : 0.f;
    o[3] = (rv[1] >> 16)     ? 1.f : 0.f;
    *(f32x4*)(dst + f) = o;
  }
}

// K4: proj conv1x1 on y = q & kvmask (hi-plane), + bias + BN + identity -> fp32 out.
// XCD-swizzled flat grid 1536: each XCD gets 16 tb values (3.1 MB q spikes L2-resident).
__global__ __launch_bounds__(256) void k4_proj(
    const u16* __restrict__ qspk, const u16* __restrict__ kvm, const u16* __restrict__ wsplit,
    const float* __restrict__ pb,
    const float* __restrict__ gp, const float* __restrict__ bep,
    const float* __restrict__ mp, const float* __restrict__ vap,
    const float* __restrict__ x, float* __restrict__ out)
{
  const int id   = blockIdx.x;          // 0..1535
  const int xcd  = id & 7;
  const int rest = id >> 3;             // 0..191
  const int obi  = rest % 6;
  const int nb2  = (rest / 6) & 1;
  const int tbl  = rest / 12;           // 0..15
  const int tb   = xcd * 16 + tbl;
  const int ob   = obi * 64;
  const int nb   = nb2 * 128;

  __shared__ __align__(16) u16 kvmask[C_];
  for (int i = threadIdx.x; i < C_; i += 256) kvmask[i] = kvm[(size_t)tb*C_ + i];
  __syncthreads();

  const int lane = threadIdx.x & 63;
  const int w = threadIdx.x >> 6;
  const int wo = w & 1, wn = w >> 1;
  const int l15 = lane & 15, lg = lane >> 4;
  const int obw = ob + wo * 32;
  const int fo  = obw >> 4;
  const int nbl = nb + wn * 64;

  const u16* Wp = wsplit + (size_t)3*FRAGS_M_ + (size_t)lane*8;   // proj, hi plane (p=0)

  float sc[2][4], sh[2][4], pbv[2][4];
#pragma unroll
  for (int io = 0; io < 2; io++)
#pragma unroll
    for (int j = 0; j < 4; j++){
      int o = obw + io*16 + lg*4 + j;
      float s = gp[o] / sqrtf(vap[o] + 1e-5f);
      sc[io][j] = s;
      sh[io][j] = bep[o] - __fmul_rn(mp[o], s);
      pbv[io][j] = pb[o];
    }

  f32x4 acc[2][4];
#pragma unroll
  for (int io = 0; io < 2; io++)
#pragma unroll
    for (int in = 0; in < 4; in++) acc[io][in] = (f32x4){0.f,0.f,0.f,0.f};

  const u16* qb = qspk + ((size_t)(tb*CG_) + lg)*2048 + (size_t)(nbl + l15)*8;

  for (int k = 0; k < 12; k++){
    bf16x8 a0 = *(const bf16x8*)(Wp + (size_t)(((fo    )*12 + k)*3)*512);
    bf16x8 a1 = *(const bf16x8*)(Wp + (size_t)(((fo + 1)*12 + k)*3)*512);
    u32x4 mv = *(const u32x4*)&kvmask[k*32 + lg*8];
    bf16x8 bb[4];
#pragma unroll
    for (int in = 0; in < 4; in++){
      u32x4 qv = *(const u32x4*)(qb + (size_t)k*8192 + in*128);
      u32x4 yv = qv & mv;
      bb[in] = __builtin_bit_cast(bf16x8, yv);
    }
#pragma unroll
    for (int in = 0; in < 4; in++){
      acc[0][in] = __builtin_amdgcn_mfma_f32_16x16x32_bf16(a0, bb[in], acc[0][in], 0, 0, 0);
      acc[1][in] = __builtin_amdgcn_mfma_f32_16x16x32_bf16(a1, bb[in], acc[1][in], 0, 0, 0);
    }
  }

#pragma unroll
  for (int io = 0; io < 2; io++)
#pragma unroll
    for (int in = 0; in < 4; in++){
      int n = nbl + in*16 + l15;
#pragma unroll
      for (int j = 0; j < 4; j++){
        int o = obw + io*16 + lg*4 + j;
        size_t off = ((size_t)tb*C_ + o)*N_ + n;
        float z = __fadd_rn(acc[io][in][j], pbv[io][j]);
        z = __fmul_rn(z, sc[io][j]);
        z = __fadd_rn(z, sh[io][j]);
        z = __fadd_rn(z, x[off]);
        out[off] = z;
      }
    }
}

extern "C" void kernel_launch(void* const* d_in, const int* in_sizes, int n_in,
                              void* d_out, int out_size, void* d_ws, size_t ws_size,
                              hipStream_t stream)
{
  (void)in_sizes; (void)n_in; (void)out_size; (void)ws_size;
  const float* x   = (const float*)d_in[0];
  const float* qw  = (const float*)d_in[1];
  const float* qg  = (const float*)d_in[2];
  const float* qbe = (const float*)d_in[3];
  const float* qm  = (const float*)d_in[4];
  const float* qva = (const float*)d_in[5];
  const float* kw  = (const float*)d_in[6];
  const float* kg  = (const float*)d_in[7];
  const float* kbe = (const float*)d_in[8];
  const float* km  = (const float*)d_in[9];
  const float* kva = (const float*)d_in[10];
  const float* vw  = (const float*)d_in[11];
  const float* vg  = (const float*)d_in[12];
  const float* vbe = (const float*)d_in[13];
  const float* vm  = (const float*)d_in[14];
  const float* vva = (const float*)d_in[15];
  const float* pw  = (const float*)d_in[16];
  const float* pb  = (const float*)d_in[17];
  const float* pg  = (const float*)d_in[18];
  const float* pbe = (const float*)d_in[19];
  const float* pm  = (const float*)d_in[20];
  const float* pva = (const float*)d_in[21];

  float* out  = (float*)d_out;
  float* vout = out + ELEMS_;          // second output: v spikes, fp32, head layout

  // packed v spikes use the first-output region as scratch (k4 overwrites it last)
  u16* vspk = (u16*)d_out;

  u16* wsplit = (u16*)d_ws;                    // 4 * FRAGS_M_ u16 = 3.54 MB
  u16* xs   = wsplit + (size_t)4*FRAGS_M_;
  u16* qspk = xs   + ELEMS_;
  u16* kspk = qspk + ELEMS_;
  u16* kvm  = kspk + ELEMS_;                   // 4*32*384 u16

  k01_prep<<<dim3(1824), 256, 0, stream>>>(x, qw, kw, vw, pw, wsplit, xs);
  k2_branch<<<dim3(2304), 256, 0, stream>>>(xs, wsplit,
      qg, qbe, qm, qva,
      kg, kbe, km, kva,
      vg, vbe, vm, vva,
      qspk, kspk, vspk);
  k3_kv<<<dim3(384), 256, 0, stream>>>(kspk, vspk, kvm);
  k5_vtrans<<<dim3(T_*B_, NH_), 256, 0, stream>>>(vspk, vout);
  k4_proj<<<dim3(1536), 256, 0, stream>>>(qspk, kvm, wsplit,
      pb, pg, pbe, pm, pva, x, out);
}

// Round 15
// 129.768 us; speedup vs baseline: 1.2564x; 1.0683x over previous
//
#include <hip/hip_runtime.h>

#define T_ 4
#define B_ 32
#define C_ 384
#define N_ 256
#define NH_ 8
#define DH_ 48
#define CG_ 48                          // C_/8
#define WELE_ 147456                    // C_*C_
#define FRAGS_M_ 442368                 // 24 o16 * 12 k32 * 3 planes * 512 u16
#define ELEMS_ ((size_t)T_*B_*C_*N_)    // 12582912 per tensor

typedef __bf16 bf16x8 __attribute__((ext_vector_type(8)));
typedef float  f32x4  __attribute__((ext_vector_type(4)));
typedef unsigned int u32x4 __attribute__((ext_vector_type(4)));
typedef unsigned int u32x2 __attribute__((ext_vector_type(2)));
typedef unsigned short u16;

__device__ __forceinline__ float bf2f(u16 h){
  unsigned u = ((unsigned)h) << 16;
  return __builtin_bit_cast(float, u);
}
__device__ __forceinline__ u16 f2bf(float f){
  unsigned u = __builtin_bit_cast(unsigned, f);
  u += 0x7FFFu + ((u >> 16) & 1u);
  return (u16)(u >> 16);
}

// K01 fused: blocks 0..287 = weight split (k0), blocks 288..1823 = input LIF (k1).
__global__ __launch_bounds__(256) void k01_prep(
    const float* __restrict__ x,
    const float* __restrict__ wq, const float* __restrict__ wk,
    const float* __restrict__ wv, const float* __restrict__ wp,
    u16* __restrict__ ws, u16* __restrict__ xs)
{
  const int blk = blockIdx.x;
  if (blk < 288){
    const int m = blk / 72;
    const int tid = (blk % 72) * 256 + threadIdx.x;     // 0..18431
    const float* W = (m == 0) ? wq : (m == 1) ? wk : (m == 2) ? wv : wp;
    const int fo   = tid / 768;
    const int rem  = tid % 768;
    const int k32  = rem / 64;
    const int lane = rem % 64;
    const int row  = fo*16 + (lane & 15);
    const int col  = k32*32 + (lane >> 4)*8;
    const float* src = W + (size_t)row*C_ + col;

    u16 hi8[8], mi8[8], lo8[8];
#pragma unroll
    for (int e = 0; e < 8; e++){
      float w = src[e];
      u16 hi = f2bf(w);  float r1 = w  - bf2f(hi);
      u16 mi = f2bf(r1); float r2 = r1 - bf2f(mi);
      u16 lo = f2bf(r2);
      hi8[e] = hi; mi8[e] = mi; lo8[e] = lo;
    }
    u16* dst = ws + (size_t)m*FRAGS_M_ + (size_t)((fo*12 + k32)*3)*512 + (size_t)lane*8;
    u32x4 pk;
#pragma unroll
    for (int p = 0; p < 3; p++){
      const u16* s = (p == 0) ? hi8 : (p == 1) ? mi8 : lo8;
      pk[0] = (unsigned)s[0] | ((unsigned)s[1] << 16);
      pk[1] = (unsigned)s[2] | ((unsigned)s[3] << 16);
      pk[2] = (unsigned)s[4] | ((unsigned)s[5] << 16);
      pk[3] = (unsigned)s[6] | ((unsigned)s[7] << 16);
      *(u32x4*)(dst + (size_t)p*512) = pk;
    }
  } else {
    const int bid = blk - 288;          // 0..1535
    const int b = bid / CG_, cg = bid % CG_;
    const int n = threadIdx.x;
    const int c0 = cg * 8;
    float v[8];
#pragma unroll
    for (int i = 0; i < 8; i++) v[i] = 0.f;
#pragma unroll
    for (int t = 0; t < T_; t++){
      const float* xp = x + (((size_t)(t*B_ + b))*C_ + c0)*N_ + n;
      u16 sp[8];
#pragma unroll
      for (int i = 0; i < 8; i++){
        float xv = xp[(size_t)i * N_];
        float vv = v[i] + (xv - v[i]) * 0.5f;
        bool s = vv >= 1.0f;
        sp[i] = s ? (u16)0x3F80u : (u16)0u;
        v[i] = s ? 0.f : vv;
      }
      u32x4 pk;
      pk[0] = (unsigned)sp[0] | ((unsigned)sp[1] << 16);
      pk[1] = (unsigned)sp[2] | ((unsigned)sp[3] << 16);
      pk[2] = (unsigned)sp[4] | ((unsigned)sp[5] << 16);
      pk[3] = (unsigned)sp[6] | ((unsigned)sp[7] << 16);
      *(u32x4*)(xs + ((size_t)((t*B_ + b)*CG_ + cg))*2048 + (size_t)n*8) = pk;
    }
  }
}

// K2: fused q/k/v conv1x1 (16x16x32, 3-plane split) + BN + LIF.  [R7 structure]
// + T5 s_setprio around each k-step's MFMA cluster: waves are barrier-free and
// independent (attn-like regime where setprio measured +4-7%), so the CU scheduler
// can favor MFMA-issuing waves over load-issuing ones.
__global__ __launch_bounds__(256) void k2_branch(
    const u16* __restrict__ xs, const u16* __restrict__ wsplit,
    const float* __restrict__ gq, const float* __restrict__ beq, const float* __restrict__ mq, const float* __restrict__ vaq,
    const float* __restrict__ gk, const float* __restrict__ bek, const float* __restrict__ mk, const float* __restrict__ vak,
    const float* __restrict__ gv, const float* __restrict__ bev, const float* __restrict__ mv, const float* __restrict__ vav,
    u16* __restrict__ qspk, u16* __restrict__ kspk, u16* __restrict__ vspk)
{
  const int id   = blockIdx.x;          // 0..2303
  const int xcd  = id & 7;
  const int rest = id >> 3;             // 0..287
  const int obi  = rest % 18;           // o-tile of 64
  const int nb4  = (rest / 18) & 3;     // n-tile of 64
  const int bloc = rest / 72;           // 0..3
  const int b    = xcd * 4 + bloc;
  const int ob   = obi * 64;
  const int nb   = nb4 * 64;

  const int lane = threadIdx.x & 63;
  const int w = threadIdx.x >> 6;
  const int wo = w & 1, wn = w >> 1;
  const int l15 = lane & 15, lg = lane >> 4;
  const int branch = ob / C_;
  const int obr = (ob % C_) + wo * 32;       // branch-local o base for this wave
  const int fo  = obr >> 4;                  // fragment o16 index; this wave: fo, fo+1

  const float *G, *Be, *M, *Va; u16* spdst;
  if (branch == 0){ G=gq; Be=beq; M=mq; Va=vaq; spdst=qspk; }
  else if (branch == 1){ G=gk; Be=bek; M=mk; Va=vak; spdst=kspk; }
  else { G=gv; Be=bev; M=mv; Va=vav; spdst=vspk; }

  const u16* Wb = wsplit + (size_t)branch*FRAGS_M_ + (size_t)lane*8;
  const int nbl = nb + wn * 32;              // this wave's 32-wide n base

  // per-t spike base (lane-resolved): + k*8192 + in*128 gives the B-fragment
  const u16* xbt[T_];
#pragma unroll
  for (int t = 0; t < T_; t++)
    xbt[t] = xs + ((size_t)((t*B_ + b)*CG_) + lg)*2048 + (size_t)(nbl + l15)*8;

  f32x4 acc[T_][2][2];
#pragma unroll
  for (int t = 0; t < T_; t++)
#pragma unroll
    for (int io = 0; io < 2; io++)
#pragma unroll
      for (int in = 0; in < 2; in++) acc[t][io][in] = (f32x4){0.f,0.f,0.f,0.f};

  for (int k = 0; k < 12; k++){
    bf16x8 wf[2][3];           // [io][plane: 0 hi,1 mid,2 lo]
#pragma unroll
    for (int io = 0; io < 2; io++)
#pragma unroll
      for (int p = 0; p < 3; p++)
        wf[io][p] = *(const bf16x8*)(Wb + (size_t)(((fo + io)*12 + k)*3 + p)*512);

    bf16x8 bb[T_][2];
#pragma unroll
    for (int t = 0; t < T_; t++)
#pragma unroll
      for (int in = 0; in < 2; in++)
        bb[t][in] = *(const bf16x8*)(xbt[t] + (size_t)k*8192 + in*128);

    __builtin_amdgcn_s_setprio(1);
#pragma unroll
    for (int t = 0; t < T_; t++){
#pragma unroll
      for (int in = 0; in < 2; in++){
        acc[t][0][in] = __builtin_amdgcn_mfma_f32_16x16x32_bf16(wf[0][2], bb[t][in], acc[t][0][in], 0, 0, 0);
        acc[t][0][in] = __builtin_amdgcn_mfma_f32_16x16x32_bf16(wf[0][1], bb[t][in], acc[t][0][in], 0, 0, 0);
        acc[t][0][in] = __builtin_amdgcn_mfma_f32_16x16x32_bf16(wf[0][0], bb[t][in], acc[t][0][in], 0, 0, 0);
        acc[t][1][in] = __builtin_amdgcn_mfma_f32_16x16x32_bf16(wf[1][2], bb[t][in], acc[t][1][in], 0, 0, 0);
        acc[t][1][in] = __builtin_amdgcn_mfma_f32_16x16x32_bf16(wf[1][1], bb[t][in], acc[t][1][in], 0, 0, 0);
        acc[t][1][in] = __builtin_amdgcn_mfma_f32_16x16x32_bf16(wf[1][0], bb[t][in], acc[t][1][in], 0, 0, 0);
      }
    }
    __builtin_amdgcn_s_setprio(0);
  }

  // epilogue: BN + LIF recurrence over t, packed bf16 spike store (all branches)
  float sc[2][4], sh[2][4];
#pragma unroll
  for (int io = 0; io < 2; io++)
#pragma unroll
    for (int j = 0; j < 4; j++){
      int o = obr + io*16 + lg*4 + j;
      float s = G[o] / sqrtf(Va[o] + 1e-5f);
      sc[io][j] = s;
      sh[io][j] = Be[o] - __fmul_rn(M[o], s);
    }

  float vm[2][2][4];
#pragma unroll
  for (int io = 0; io < 2; io++)
#pragma unroll
    for (int in = 0; in < 2; in++)
#pragma unroll
      for (int j = 0; j < 4; j++) vm[io][in][j] = 0.f;

#pragma unroll
  for (int t = 0; t < T_; t++){
#pragma unroll
    for (int io = 0; io < 2; io++)
#pragma unroll
      for (int in = 0; in < 2; in++){
        int n = nbl + in*16 + l15;
        u16 sp[4];
#pragma unroll
        for (int j = 0; j < 4; j++){
          float z = __fadd_rn(__fmul_rn(acc[t][io][in][j], sc[io][j]), sh[io][j]);
          float vv = vm[io][in][j];
          vv = vv + (z - vv) * 0.5f;
          bool s = vv >= 1.0f;
          sp[j] = s ? (u16)0x3F80u : (u16)0u;
          vm[io][in][j] = s ? 0.f : vv;
        }
        u32x2 pk;
        pk[0] = (unsigned)sp[0] | ((unsigned)sp[1] << 16);
        pk[1] = (unsigned)sp[2] | ((unsigned)sp[3] << 16);
        int od = obr + io*16 + lg*4;
        u16* dst = spdst + (size_t)((t*B_ + b)*CG_ + (od >> 3))*2048 + (size_t)n*8 + (od & 7);
        *(u32x2*)dst = pk;
      }
  }
}

// K35 merged: blocks 0..383 = k3 (kv reduce + LIF masks); blocks 384..1407 = k5 (v expand).
__global__ __launch_bounds__(256) void k35_kv_vtrans(
    const u16* __restrict__ kspk, const u16* __restrict__ vspk,
    u16* __restrict__ kvm, float* __restrict__ vout)
{
  const int blk = blockIdx.x;
  if (blk < 384){
    // k3: kv = sum_n k*v per (t,b,c) via AND, LIF(0.5), emit 0xFFFF/0 masks [t][b][c]
    const int wid  = (int)(((unsigned)blk * 256 + threadIdx.x) >> 6); // 0..1535
    const int lane = threadIdx.x & 63;
    const int b = wid / CG_, cg = wid % CG_;
    float u[8];
#pragma unroll
    for (int i = 0; i < 8; i++) u[i] = 0.f;

#pragma unroll
    for (int t = 0; t < T_; t++){
      int cnt[8];
#pragma unroll
      for (int i = 0; i < 8; i++) cnt[i] = 0;
      const size_t rowoff = (size_t)((t*B_ + b)*CG_ + cg)*2048;
      const u16* kp = kspk + rowoff;
      const u16* vp = vspk + rowoff;
#pragma unroll
      for (int j = 0; j < 4; j++){
        int n = j*64 + lane;
        u32x4 kk = *(const u32x4*)(kp + (size_t)n*8);
        u32x4 vv = *(const u32x4*)(vp + (size_t)n*8);
#pragma unroll
        for (int wd = 0; wd < 4; wd++){
          unsigned both = kk[wd] & vv[wd];
          cnt[2*wd]   += (both & 0xFFFFu) ? 1 : 0;
          cnt[2*wd+1] += (both >> 16)     ? 1 : 0;
        }
      }
#pragma unroll
      for (int i = 0; i < 8; i++){
#pragma unroll
        for (int off = 32; off >= 1; off >>= 1) cnt[i] += __shfl_xor(cnt[i], off, 64);
      }
      u16 mk[8];
#pragma unroll
      for (int i = 0; i < 8; i++){
        float kvf = (float)cnt[i];
        float uu = u[i] + (kvf - u[i]) * 0.5f;
        bool s = uu >= 0.5f;
        mk[i] = s ? (u16)0xFFFFu : (u16)0u;
        u[i] = s ? 0.f : uu;
      }
      if (lane == 0){
        u32x4 pk;
        pk[0] = (unsigned)mk[0] | ((unsigned)mk[1] << 16);
        pk[1] = (unsigned)mk[2] | ((unsigned)mk[3] << 16);
        pk[2] = (unsigned)mk[4] | ((unsigned)mk[5] << 16);
        pk[3] = (unsigned)mk[6] | ((unsigned)mk[7] << 16);
        *(u32x4*)(kvm + (size_t)(t*B_ + b)*C_ + cg*8) = pk;
      }
    }
  } else {
    // k5: expand packed v spikes -> fp32 head layout [t][b][h][n][dh]
    const int blk2 = blk - 384;         // 0..1023
    const int tb = blk2 >> 3, h = blk2 & 7;
    const u16* src = vspk + ((size_t)tb*CG_ + h*6)*2048;
    float* dst = vout + ((size_t)tb*NH_ + h)*(N_*DH_);
#pragma unroll
    for (int i = 0; i < 12; i++){
      int f = i*1024 + threadIdx.x*4;
      int n = f / DH_;
      int d = f - n*DH_;
      u32x2 rv = *(const u32x2*)(src + (size_t)(d >> 3)*2048 + (size_t)n*8 + (d & 7));
      f32x4 o;
      o[0] = (rv[0] & 0xFFFFu) ? 1.f : 0.f;
      o[1] = (rv[0] >> 16)     ? 1.f : 0.f;
      o[2] = (rv[1] & 0xFFFFu) ? 1.f : 0.f;
      o[3] = (rv[1] >> 16)     ? 1.f : 0.f;
      *(f32x4*)(dst + f) = o;
    }
  }
}

// K4: proj conv1x1 on y = q & kvmask (hi-plane), + bias + BN + identity -> fp32 out.
__global__ __launch_bounds__(256) void k4_proj(
    const u16* __restrict__ qspk, const u16* __restrict__ kvm, const u16* __restrict__ wsplit,
    const float* __restrict__ pb,
    const float* __restrict__ gp, const float* __restrict__ bep,
    const float* __restrict__ mp, const float* __restrict__ vap,
    const float* __restrict__ x, float* __restrict__ out)
{
  const int id   = blockIdx.x;          // 0..1535
  const int xcd  = id & 7;
  const int rest = id >> 3;             // 0..191
  const int obi  = rest % 6;
  const int nb2  = (rest / 6) & 1;
  const int tbl  = rest / 12;           // 0..15
  const int tb   = xcd * 16 + tbl;
  const int ob   = obi * 64;
  const int nb   = nb2 * 128;

  __shared__ __align__(16) u16 kvmask[C_];
  for (int i = threadIdx.x; i < C_; i += 256) kvmask[i] = kvm[(size_t)tb*C_ + i];
  __syncthreads();

  const int lane = threadIdx.x & 63;
  const int w = threadIdx.x >> 6;
  const int wo = w & 1, wn = w >> 1;
  const int l15 = lane & 15, lg = lane >> 4;
  const int obw = ob + wo * 32;
  const int fo  = obw >> 4;
  const int nbl = nb + wn * 64;

  const u16* Wp = wsplit + (size_t)3*FRAGS_M_ + (size_t)lane*8;   // proj, hi plane (p=0)

  float sc[2][4], sh[2][4], pbv[2][4];
#pragma unroll
  for (int io = 0; io < 2; io++)
#pragma unroll
    for (int j = 0; j < 4; j++){
      int o = obw + io*16 + lg*4 + j;
      float s = gp[o] / sqrtf(vap[o] + 1e-5f);
      sc[io][j] = s;
      sh[io][j] = bep[o] - __fmul_rn(mp[o], s);
      pbv[io][j] = pb[o];
    }

  f32x4 acc[2][4];
#pragma unroll
  for (int io = 0; io < 2; io++)
#pragma unroll
    for (int in = 0; in < 4; in++) acc[io][in] = (f32x4){0.f,0.f,0.f,0.f};

  const u16* qb = qspk + ((size_t)(tb*CG_) + lg)*2048 + (size_t)(nbl + l15)*8;

  for (int k = 0; k < 12; k++){
    bf16x8 a0 = *(const bf16x8*)(Wp + (size_t)(((fo    )*12 + k)*3)*512);
    bf16x8 a1 = *(const bf16x8*)(Wp + (size_t)(((fo + 1)*12 + k)*3)*512);
    u32x4 mv = *(const u32x4*)&kvmask[k*32 + lg*8];
    bf16x8 bb[4];
#pragma unroll
    for (int in = 0; in < 4; in++){
      u32x4 qv = *(const u32x4*)(qb + (size_t)k*8192 + in*128);
      u32x4 yv = qv & mv;
      bb[in] = __builtin_bit_cast(bf16x8, yv);
    }
#pragma unroll
    for (int in = 0; in < 4; in++){
      acc[0][in] = __builtin_amdgcn_mfma_f32_16x16x32_bf16(a0, bb[in], acc[0][in], 0, 0, 0);
      acc[1][in] = __builtin_amdgcn_mfma_f32_16x16x32_bf16(a1, bb[in], acc[1][in], 0, 0, 0);
    }
  }

#pragma unroll
  for (int io = 0; io < 2; io++)
#pragma unroll
    for (int in = 0; in < 4; in++){
      int n = nbl + in*16 + l15;
#pragma unroll
      for (int j = 0; j < 4; j++){
        int o = obw + io*16 + lg*4 + j;
        size_t off = ((size_t)tb*C_ + o)*N_ + n;
        float z = __fadd_rn(acc[io][in][j], pbv[io][j]);
        z = __fmul_rn(z, sc[io][j]);
        z = __fadd_rn(z, sh[io][j]);
        z = __fadd_rn(z, x[off]);
        out[off] = z;
      }
    }
}

extern "C" void kernel_launch(void* const* d_in, const int* in_sizes, int n_in,
                              void* d_out, int out_size, void* d_ws, size_t ws_size,
                              hipStream_t stream)
{
  (void)in_sizes; (void)n_in; (void)out_size; (void)ws_size;
  const float* x   = (const float*)d_in[0];
  const float* qw  = (const float*)d_in[1];
  const float* qg  = (const float*)d_in[2];
  const float* qbe = (const float*)d_in[3];
  const float* qm  = (const float*)d_in[4];
  const float* qva = (const float*)d_in[5];
  const float* kw  = (const float*)d_in[6];
  const float* kg  = (const float*)d_in[7];
  const float* kbe = (const float*)d_in[8];
  const float* km  = (const float*)d_in[9];
  const float* kva = (const float*)d_in[10];
  const float* vw  = (const float*)d_in[11];
  const float* vg  = (const float*)d_in[12];
  const float* vbe = (const float*)d_in[13];
  const float* vm  = (const float*)d_in[14];
  const float* vva = (const float*)d_in[15];
  const float* pw  = (const float*)d_in[16];
  const float* pb  = (const float*)d_in[17];
  const float* pg  = (const float*)d_in[18];
  const float* pbe = (const float*)d_in[19];
  const float* pm  = (const float*)d_in[20];
  const float* pva = (const float*)d_in[21];

  float* out  = (float*)d_out;
  float* vout = out + ELEMS_;          // second output: v spikes, fp32, head layout

  // packed v spikes use the first-output region as scratch (k4 overwrites it last)
  u16* vspk = (u16*)d_out;

  u16* wsplit = (u16*)d_ws;                    // 4 * FRAGS_M_ u16 = 3.54 MB
  u16* xs   = wsplit + (size_t)4*FRAGS_M_;
  u16* qspk = xs   + ELEMS_;
  u16* kspk = qspk + ELEMS_;
  u16* kvm  = kspk + ELEMS_;                   // 4*32*384 u16

  k01_prep<<<dim3(1824), 256, 0, stream>>>(x, qw, kw, vw, pw, wsplit, xs);
  k2_branch<<<dim3(2304), 256, 0, stream>>>(xs, wsplit,
      qg, qbe, qm, qva,
      kg, kbe, km, kva,
      vg, vbe, vm, vva,
      qspk, kspk, vspk);
  k35_kv_vtrans<<<dim3(1408), 256, 0, stream>>>(kspk, vspk, kvm, vout);
  k4_proj<<<dim3(1536), 256, 0, stream>>>(qspk, kvm, wsplit,
      pb, pg, pbe, pm, pva, x, out);
}